// Round 4
// baseline (354.988 us; speedup 1.0000x reference)
//
#include <hip/hip_runtime.h>

// N = 33554432 ; inputs: s (int32 in {0,1}), other_s (int32 in {0,1}), x (float32)
// out = mean( (s==other_s ? 1 : -1) * x )
// Pure streaming reduction: 402.7 MB read, 4 B write. Memory-bound.
// R4: per-block CONTIGUOUS partitioning (vs global grid-stride lockstep sweep).
// R1-R3 pinned at ~3 TB/s effective regardless of occupancy/batching -> the
// limit is the access structure, not wave-side parallelism.

constexpr int BLOCK = 256;
constexpr int GRID  = 1024;   // 4 blocks/CU; best config so far (R1)

__device__ __forceinline__ float signed_sum(int4 sv, int4 ov, float4 xv) {
    // s,o in {0,1}: flip sign iff s != o  ->  xor sign bit with (s^o)<<31
    float r;
    r  = __int_as_float(__float_as_int(xv.x) ^ ((sv.x ^ ov.x) << 31));
    r += __int_as_float(__float_as_int(xv.y) ^ ((sv.y ^ ov.y) << 31));
    r += __int_as_float(__float_as_int(xv.z) ^ ((sv.z ^ ov.z) << 31));
    r += __int_as_float(__float_as_int(xv.w) ^ ((sv.w ^ ov.w) << 31));
    return r;
}

__global__ __launch_bounds__(BLOCK) void disc_loss_partial(
        const int*   __restrict__ s,
        const int*   __restrict__ o,
        const float* __restrict__ x,
        float*       __restrict__ partials,
        int n4)
{
    const int4*   s4 = (const int4*)s;
    const int4*   o4 = (const int4*)o;
    const float4* x4 = (const float4*)x;

    // Block b owns int4 range [b*chunk, (b+1)*chunk): a private contiguous
    // 128 KB slice of each array, walked sequentially with BLOCK stride.
    const int chunk = (n4 + GRID - 1) / GRID;          // 8192 at N=32M
    const int begin = blockIdx.x * chunk;
    const int end   = min(begin + chunk, n4);

    float acc = 0.0f;
    int i = begin + threadIdx.x;

    // Main loop: 4 BLOCK-steps per iteration, loads batched before consumes.
    // At N=32M: exactly 8 iterations, no remainder.
    for (; i + 3 * BLOCK < end; i += 4 * BLOCK) {
        int4 sa = s4[i];             int4 sb = s4[i + BLOCK];
        int4 sc = s4[i + 2 * BLOCK]; int4 sd = s4[i + 3 * BLOCK];
        int4 oa = o4[i];             int4 ob = o4[i + BLOCK];
        int4 oc = o4[i + 2 * BLOCK]; int4 od = o4[i + 3 * BLOCK];
        float4 xa = x4[i];             float4 xb = x4[i + BLOCK];
        float4 xc = x4[i + 2 * BLOCK]; float4 xd = x4[i + 3 * BLOCK];

        acc += signed_sum(sa, oa, xa);
        acc += signed_sum(sb, ob, xb);
        acc += signed_sum(sc, oc, xc);
        acc += signed_sum(sd, od, xd);
    }
    for (; i < end; i += BLOCK)
        acc += signed_sum(s4[i], o4[i], x4[i]);

    // wave-64 shuffle reduction
    #pragma unroll
    for (int off = 32; off > 0; off >>= 1)
        acc += __shfl_down(acc, off, 64);

    __shared__ float lds[BLOCK / 64];
    int lane = threadIdx.x & 63;
    int wid  = threadIdx.x >> 6;
    if (lane == 0) lds[wid] = acc;
    __syncthreads();
    if (threadIdx.x == 0) {
        float sum = 0.0f;
        #pragma unroll
        for (int w = 0; w < BLOCK / 64; ++w) sum += lds[w];
        partials[blockIdx.x] = sum;
    }
}

__global__ __launch_bounds__(256) void disc_loss_final(
        const float* __restrict__ partials,
        float*       __restrict__ out,
        float inv_n)
{
    float acc = 0.0f;
    #pragma unroll
    for (int i = threadIdx.x; i < GRID; i += 256)
        acc += partials[i];

    #pragma unroll
    for (int off = 32; off > 0; off >>= 1)
        acc += __shfl_down(acc, off, 64);

    __shared__ float lds[4];
    int lane = threadIdx.x & 63;
    int wid  = threadIdx.x >> 6;
    if (lane == 0) lds[wid] = acc;
    __syncthreads();
    if (threadIdx.x == 0)
        out[0] = (lds[0] + lds[1] + lds[2] + lds[3]) * inv_n;
}

extern "C" void kernel_launch(void* const* d_in, const int* in_sizes, int n_in,
                              void* d_out, int out_size, void* d_ws, size_t ws_size,
                              hipStream_t stream)
{
    const int*   s = (const int*)d_in[0];
    const int*   o = (const int*)d_in[1];
    const float* x = (const float*)d_in[2];
    float* out      = (float*)d_out;
    float* partials = (float*)d_ws;   // GRID floats = 4 KB

    int n  = in_sizes[0];
    int n4 = n / 4;                   // N divisible by 4

    disc_loss_partial<<<GRID, BLOCK, 0, stream>>>(s, o, x, partials, n4);
    disc_loss_final<<<1, 256, 0, stream>>>(partials, out, 1.0f / (float)n);
}

// Round 6
// 320.430 us; speedup vs baseline: 1.1078x; 1.1078x over previous
//
#include <hip/hip_runtime.h>

// N = 33554432 ; inputs: s (int32 in {0,1}), other_s (int32 in {0,1}), x (float32)
// out = mean( (s==other_s ? 1 : -1) * x )
// R6: R5 retry — nontemporal loads via native clang ext_vector types
// (__builtin_nontemporal_load rejects HIP_vector_type wrappers).
// Probes whether the ~3.1 TB/s delivered-read plateau is cache-allocation
// overhead (helps) or a structural read-path ceiling (no-op).

constexpr int BLOCK = 256;
constexpr int GRID  = 1024;   // 4 blocks/CU; best measured config (R1, 127us)

typedef int   vi4 __attribute__((ext_vector_type(4)));
typedef float vf4 __attribute__((ext_vector_type(4)));

__global__ __launch_bounds__(BLOCK) void disc_loss_partial(
        const int*   __restrict__ s,
        const int*   __restrict__ o,
        const float* __restrict__ x,
        float*       __restrict__ partials,
        int n4)
{
    const vi4* s4 = (const vi4*)s;
    const vi4* o4 = (const vi4*)o;
    const vf4* x4 = (const vf4*)x;

    float acc = 0.0f;
    const int stride = GRID * BLOCK;   // 262144; n4 = 8388608 -> 32 iters/thread
    for (int i = blockIdx.x * BLOCK + threadIdx.x; i < n4; i += stride) {
        vi4 sv = __builtin_nontemporal_load(&s4[i]);
        vi4 ov = __builtin_nontemporal_load(&o4[i]);
        vf4 xv = __builtin_nontemporal_load(&x4[i]);
        // s,o in {0,1}: flip sign iff s != o  ->  xor sign bit with (s^o)<<31
        vi4 sgn = (sv ^ ov) << 31;
        acc += __int_as_float(__float_as_int(xv.x) ^ sgn.x);
        acc += __int_as_float(__float_as_int(xv.y) ^ sgn.y);
        acc += __int_as_float(__float_as_int(xv.z) ^ sgn.z);
        acc += __int_as_float(__float_as_int(xv.w) ^ sgn.w);
    }

    // wave-64 shuffle reduction
    #pragma unroll
    for (int off = 32; off > 0; off >>= 1)
        acc += __shfl_down(acc, off, 64);

    __shared__ float lds[BLOCK / 64];
    int lane = threadIdx.x & 63;
    int wid  = threadIdx.x >> 6;
    if (lane == 0) lds[wid] = acc;
    __syncthreads();
    if (threadIdx.x == 0) {
        float sum = 0.0f;
        #pragma unroll
        for (int w = 0; w < BLOCK / 64; ++w) sum += lds[w];
        partials[blockIdx.x] = sum;
    }
}

__global__ __launch_bounds__(256) void disc_loss_final(
        const float* __restrict__ partials,
        float*       __restrict__ out,
        float inv_n)
{
    float acc = 0.0f;
    #pragma unroll
    for (int i = threadIdx.x; i < GRID; i += 256)
        acc += partials[i];

    #pragma unroll
    for (int off = 32; off > 0; off >>= 1)
        acc += __shfl_down(acc, off, 64);

    __shared__ float lds[4];
    int lane = threadIdx.x & 63;
    int wid  = threadIdx.x >> 6;
    if (lane == 0) lds[wid] = acc;
    __syncthreads();
    if (threadIdx.x == 0)
        out[0] = (lds[0] + lds[1] + lds[2] + lds[3]) * inv_n;
}

extern "C" void kernel_launch(void* const* d_in, const int* in_sizes, int n_in,
                              void* d_out, int out_size, void* d_ws, size_t ws_size,
                              hipStream_t stream)
{
    const int*   s = (const int*)d_in[0];
    const int*   o = (const int*)d_in[1];
    const float* x = (const float*)d_in[2];
    float* out      = (float*)d_out;
    float* partials = (float*)d_ws;   // GRID floats = 4 KB

    int n  = in_sizes[0];
    int n4 = n / 4;                   // N divisible by 4

    disc_loss_partial<<<GRID, BLOCK, 0, stream>>>(s, o, x, partials, n4);
    disc_loss_final<<<1, 256, 0, stream>>>(partials, out, 1.0f / (float)n);
}